// Round 13
// baseline (844.362 us; speedup 1.0000x reference)
//
#include <hip/hip_runtime.h>
#include <hip/hip_cooperative_groups.h>
#include <math.h>

namespace cg = cooperative_groups;

typedef unsigned short ushort_t;
typedef unsigned int uint_t;
typedef __attribute__((ext_vector_type(8))) short short8;
typedef __attribute__((ext_vector_type(4))) float f32x4;

#define ACT_NONE     0
#define ACT_SOFTPLUS 1
#define ACT_SILU     2
#define ACT_SIGMOID  3
#define ACT_GELU     4
#define ACT_RFF      5
#define ACT_CAUSAL   6

__device__ __forceinline__ ushort_t f2b(float f) {
    union { float f; uint_t u; } v; v.f = f;
    uint_t u = v.u;
    uint_t r = (u + 0x7FFFu + ((u >> 16) & 1u)) >> 16;
    return (ushort_t)r;
}
__device__ __forceinline__ float b2f(ushort_t h) {
    union { uint_t u; float f; } v; v.u = ((uint_t)h) << 16;
    return v.f;
}
__device__ __forceinline__ void split2(float v, ushort_t& h0, ushort_t& h1) {
    h0 = f2b(v); h1 = f2b(v - b2f(h0));
}
__device__ __forceinline__ void split3(float v, ushort_t& h0, ushort_t& h1, ushort_t& h2) {
    h0 = f2b(v); float r1 = v - b2f(h0);
    h1 = f2b(r1); h2 = f2b(r1 - b2f(h1));
}

__device__ __forceinline__ float fast_erf(float x) {
    float ax = fabsf(x);
    float t = 1.f / (1.f + 0.3275911f * ax);
    float poly = t * (0.254829592f + t * (-0.284496736f + t * (1.421413741f
               + t * (-1.453152027f + t * 1.061405429f))));
    float er = 1.f - poly * __expf(-ax * ax);
    return copysignf(er, x);
}

__device__ __forceinline__ float act_apply(float v, int act) {
    switch (act) {
        case ACT_SOFTPLUS: return v > 0.f ? v + __logf(1.f + __expf(-v)) : __logf(1.f + __expf(v));
        case ACT_SILU:     return v / (1.f + __expf(-v));
        case ACT_SIGMOID:  return 1.f / (1.f + __expf(-v));
        case ACT_GELU:     return 0.5f * v * (1.f + fast_erf(v * 0.7071067811865475f));
        default:           return v;
    }
}

#define LDK2 72
#define TSTRIDE 66

struct GJob {
    const ushort_t *A0, *A1, *A2, *B0, *B1, *B2;
    const float* bias;
    float* outF;
    ushort_t *o0, *o1, *o2, *t0, *t1;
    int lda, ldb, ldo, ldob, colOffB, act, ns, K, N;
    int nx, ny, base, zmod;
    int sAb1, sAb2, sBb1, sBb2, sOb, sObB, sTb;
};

// ---------------------------------------------------------------------------
// GEMM body (one virtual block).
// ---------------------------------------------------------------------------
template<int NSMAX>
__device__ __noinline__ void gemm_body(int bid, const GJob* js, int nj, ushort_t* ldsbuf)
{
    ushort_t (*sA)[64 * LDK2] = (ushort_t(*)[64 * LDK2])ldsbuf;
    ushort_t (*sB)[64 * LDK2] = (ushort_t(*)[64 * LDK2])(ldsbuf + NSMAX * 64 * LDK2);

    GJob J = js[0];
    for (int j = nj - 1; j > 0; --j) if (bid >= js[j].base) { J = js[j]; break; }

    int rel = bid - J.base;
    int perz = J.nx * J.ny;
    int bz = rel / perz; rel -= bz * perz;
    int by = rel / J.nx, bx = rel - by * J.nx;
    int zq = bz / J.zmod, zr = bz - zq * J.zmod;

    const ushort_t* As[3] = {J.A0, J.A1, J.A2};
    const ushort_t* Bs[3] = {J.B0, J.B1, J.B2};
    long offA = (long)zq * J.sAb1 + (long)zr * J.sAb2;
    long offB = (long)zq * J.sBb1 + (long)zr * J.sBb2;
    #pragma unroll
    for (int s = 0; s < NSMAX; ++s) { As[s] += offA; Bs[s] += offB; }
    float* outF = J.outF ? J.outF + (long)bz * J.sOb : nullptr;
    ushort_t* o0 = J.o0 ? J.o0 + (long)bz * J.sObB : nullptr;
    ushort_t* o1 = J.o1 ? J.o1 + (long)bz * J.sObB : nullptr;
    ushort_t* o2 = J.o2 ? J.o2 + (long)bz * J.sObB : nullptr;

    const int m0 = by * 64, n0 = bx * 64;
    const int tid = threadIdx.x, lane = tid & 63, wid = tid >> 6;
    const int wr = (wid >> 1) * 32, wc = (wid & 1) * 32;
    const int lr = lane & 15, lk = (lane >> 4) * 8;
    const int rS = tid >> 3, c8 = (tid & 7) * 8;

    uint4 rA[NSMAX][2], rB[NSMAX][2];

    auto LOAD = [&](int k0) {
        #pragma unroll
        for (int s = 0; s < NSMAX; ++s) if (s < J.ns) {
            #pragma unroll
            for (int p = 0; p < 2; ++p) {
                rA[s][p] = *(const uint4*)(As[s] + (long)(m0 + rS + 32 * p) * J.lda + k0 + c8);
                rB[s][p] = *(const uint4*)(Bs[s] + (long)(n0 + rS + 32 * p) * J.ldb + k0 + c8);
            }
        }
    };
    auto STORE = [&]() {
        #pragma unroll
        for (int s = 0; s < NSMAX; ++s) if (s < J.ns) {
            #pragma unroll
            for (int p = 0; p < 2; ++p) {
                *(uint4*)&sA[s][(rS + 32 * p) * LDK2 + c8] = rA[s][p];
                *(uint4*)&sB[s][(rS + 32 * p) * LDK2 + c8] = rB[s][p];
            }
        }
    };

    f32x4 acc[2][2];
    #pragma unroll
    for (int i = 0; i < 2; ++i)
        #pragma unroll
        for (int j = 0; j < 2; ++j)
            acc[i][j] = (f32x4){0.f, 0.f, 0.f, 0.f};

    const int niter = J.K >> 6;
    LOAD(0);
    for (int it = 0; it < niter; ++it) {
        if (it) __syncthreads();
        STORE();
        __syncthreads();
        if (it + 1 < niter) LOAD((it + 1) << 6);
        #pragma unroll
        for (int ks = 0; ks < 2; ++ks) {
            short8 af[NSMAX][2], bg[NSMAX][2];
            #pragma unroll
            for (int s = 0; s < NSMAX; ++s) if (s < J.ns) {
                af[s][0] = *(const short8*)&sA[s][(wr + lr) * LDK2 + ks * 32 + lk];
                af[s][1] = *(const short8*)&sA[s][(wr + 16 + lr) * LDK2 + ks * 32 + lk];
                bg[s][0] = *(const short8*)&sB[s][(wc + lr) * LDK2 + ks * 32 + lk];
                bg[s][1] = *(const short8*)&sB[s][(wc + 16 + lr) * LDK2 + ks * 32 + lk];
            }
            #pragma unroll
            for (int i = 0; i < 2; ++i) {
                #pragma unroll
                for (int j = 0; j < 2; ++j) {
                    acc[i][j] = __builtin_amdgcn_mfma_f32_16x16x32_bf16(af[0][i], bg[0][j], acc[i][j], 0, 0, 0);
                    if constexpr (NSMAX >= 2) if (J.ns >= 2) {
                        acc[i][j] = __builtin_amdgcn_mfma_f32_16x16x32_bf16(af[0][i], bg[1][j], acc[i][j], 0, 0, 0);
                        acc[i][j] = __builtin_amdgcn_mfma_f32_16x16x32_bf16(af[1][i], bg[0][j], acc[i][j], 0, 0, 0);
                    }
                    if constexpr (NSMAX >= 3) if (J.ns >= 3) {
                        acc[i][j] = __builtin_amdgcn_mfma_f32_16x16x32_bf16(af[0][i], bg[2][j], acc[i][j], 0, 0, 0);
                        acc[i][j] = __builtin_amdgcn_mfma_f32_16x16x32_bf16(af[1][i], bg[1][j], acc[i][j], 0, 0, 0);
                        acc[i][j] = __builtin_amdgcn_mfma_f32_16x16x32_bf16(af[2][i], bg[0][j], acc[i][j], 0, 0, 0);
                    }
                }
            }
        }
    }

    ushort_t* sAf = &sA[0][0];
    ushort_t* sBf = &sB[0][0];
    const bool hasT = (J.t0 != nullptr);
    if (hasT) __syncthreads();

    #pragma unroll
    for (int i = 0; i < 2; ++i) {
        #pragma unroll
        for (int j = 0; j < 2; ++j) {
            #pragma unroll
            for (int rr = 0; rr < 4; ++rr) {
                int rl2 = wr + i * 16 + (lane >> 4) * 4 + rr;
                int cl2 = wc + j * 16 + lr;
                int row = m0 + rl2;
                int col = n0 + cl2;
                if (col >= J.N) continue;
                float v = acc[i][j][rr];
                if (J.bias) v += J.bias[col];
                if (J.act == ACT_RFF) {
                    const float sc = 0.08838834764831845f;
                    float sv_, cv_;
                    __sincosf(v, &sv_, &cv_);
                    float cv = sc * cv_, sv = sc * sv_;
                    ushort_t ch = f2b(cv), sh = f2b(sv);
                    ushort_t cL = f2b(cv - b2f(ch)), sL = f2b(sv - b2f(sh));
                    long oc = (long)row * J.ldob + col, os = oc + J.N;
                    o0[oc] = ch; o0[os] = sh;
                    o1[oc] = cL; o1[os] = sL;
                    if (hasT) {
                        sAf[cl2 * TSTRIDE + rl2] = ch;
                        sAf[4224 + cl2 * TSTRIDE + rl2] = cL;
                        sBf[cl2 * TSTRIDE + rl2] = sh;
                        sBf[4224 + cl2 * TSTRIDE + rl2] = sL;
                    }
                    continue;
                }
                if (J.act == ACT_CAUSAL) { if (col > row) v = 0.f; }
                else v = act_apply(v, J.act);
                if (outF) outF[(long)row * J.ldo + col] = v;
                if (o0) {
                    long o = (long)row * J.ldob + J.colOffB + col;
                    ushort_t h0 = f2b(v); o0[o] = h0;
                    if (o1) {
                        float r1 = v - b2f(h0);
                        ushort_t h1 = f2b(r1); o1[o] = h1;
                        if (o2) o2[o] = f2b(r1 - b2f(h1));
                    }
                }
                if (hasT) {
                    ushort_t h0 = f2b(v);
                    sAf[cl2 * TSTRIDE + rl2] = h0;
                    sAf[4224 + cl2 * TSTRIDE + rl2] = f2b(v - b2f(h0));
                }
            }
        }
    }

    if (hasT) {
        __syncthreads();
        int bb = m0 >> 10, tl0 = m0 & 1023;
        int cl = tid >> 2, seg = tid & 3;
        int ngroups = (J.act == ACT_RFF) ? 2 : 1;
        for (int g = 0; g < ngroups; ++g) {
            const ushort_t* th = (g ? sBf : sAf) + cl * TSTRIDE + seg * 16;
            const ushort_t* tl = th + 4224;
            long gcol = (long)(n0 + cl) + (long)g * J.N;
            long addr = (long)bb * J.sTb + gcol * 1024 + tl0 + seg * 16;
            uint_t wh[8], wl[8];
            #pragma unroll
            for (int k2 = 0; k2 < 8; ++k2) {
                wh[k2] = (uint_t)th[2 * k2] | ((uint_t)th[2 * k2 + 1] << 16);
                wl[k2] = (uint_t)tl[2 * k2] | ((uint_t)tl[2 * k2 + 1] << 16);
            }
            *(uint4*)(J.t0 + addr)     = *(uint4*)&wh[0];
            *(uint4*)(J.t0 + addr + 8) = *(uint4*)&wh[4];
            *(uint4*)(J.t1 + addr)     = *(uint4*)&wl[0];
            *(uint4*)(J.t1 + addr + 8) = *(uint4*)&wl[4];
        }
    }
    __syncthreads();
}

// ---------------------------------------------------------------------------
// SSM pass body (one virtual block).  PASS=1 or 3.
// ---------------------------------------------------------------------------
template<int PASS>
__device__ __noinline__ void ssm_body(int bx2, const float* x, const float* delta,
                                      const float* BtCt, const float* A_log,
                                      float* hend, float* Pst, const float* hstart,
                                      ushort_t* giH, ushort_t* giL, ushort_t* ldsbuf)
{
    const int dblk = bx2 & 15, cc = (bx2 >> 4) & 15, bb2 = bx2 >> 8;
    const int tid2 = threadIdx.x;
    const int nn = tid2 & 15, dl = tid2 >> 4;
    const int dd = dblk * 16 + dl;
    float* sd  = (float*)ldsbuf;
    float* sx2 = sd + 1024;
    float* sB2 = sx2 + 1024;
    float* sC2 = sB2 + 1024;
    #pragma unroll
    for (int it = 0; it < 4; ++it) {
        int i2 = it * 256 + tid2;
        int t2 = i2 >> 4, j2 = i2 & 15;
        long row = (long)bb2 * 1024 + cc * 64 + t2;
        sd[t2 * 16 + j2]  = delta[row * 256 + dblk * 16 + j2];
        sx2[t2 * 16 + j2] = x[row * 256 + dblk * 16 + j2];
        sB2[t2 * 16 + j2] = BtCt[row * 32 + j2];
        if (PASS == 3) sC2[t2 * 16 + j2] = BtCt[row * 32 + 16 + j2];
    }
    __syncthreads();
    const float acoef = -__expf(A_log[dd * 16 + nn]);
    float h = 0.f, P = 1.f;
    if (PASS == 3) h = hstart[((long)(bb2 * 16 + cc) << 12) + dd * 16 + nn];
    for (int t2 = 0; t2 < 64; ++t2) {
        float dlt = sd[t2 * 16 + dl];
        float a2 = __expf(dlt * acoef);
        h = a2 * h + (dlt * sx2[t2 * 16 + dl]) * sB2[t2 * 16 + nn];
        if (PASS == 1) P *= a2;
        if (PASS == 3) {
            float part = sC2[t2 * 16 + nn] * h;
            #pragma unroll
            for (int msk = 8; msk; msk >>= 1) part += __shfl_xor(part, msk, 16);
            if (nn == 0) {
                long row = (long)bb2 * 1024 + cc * 64 + t2;
                ushort_t hh = f2b(part);
                giH[row * 576 + dd] = hh;
                giL[row * 576 + dd] = f2b(part - b2f(hh));
            }
        }
    }
    if (PASS == 1) {
        long idx = ((long)(bb2 * 16 + cc) << 12) + dd * 16 + nn;
        hend[idx] = h;
        Pst[idx] = P;
    }
    __syncthreads();
}

// ---------------------------------------------------------------------------
struct MegaArgs {
    const float *x, *A_log, *Wxp, *Wdt, *b_dt, *Wc, *Wq, *Wk, *Wv, *Wo, *omega,
                *Wg1, *bg1, *Wg2, *bg2, *ln1g, *ln1b, *ln2g, *ln2b,
                *Wf1, *bf1, *Wf2, *bf2;
    char* B;
    float* out;
};

#define PUS(off) ((ushort_t*)(A.B + (off)))
#define PF(off)  ((float*)(A.B + (off)))

__global__ void __launch_bounds__(256)
mega(MegaArgs A)
{
    cg::grid_group grid = cg::this_grid();
    __shared__ ushort_t ldsbuf[3 * 2 * 64 * LDK2];
    const int NB = gridDim.x;
    const int bid = blockIdx.x;
    const int tid = threadIdx.x;

    ushort_t *x0 = PUS(0), *x1 = PUS(1048576), *x2 = PUS(2097152);
    ushort_t *Qp_hi = PUS(3145728), *Qp_lo = PUS(5242880);
    ushort_t *Kp_hi = PUS(7340032), *Kp_lo = PUS(9437184);
    ushort_t *KpT_hi = PUS(11534336), *KpT_lo = PUS(13631488);
    ushort_t *VT_hi = PUS(15728640), *VT_lo = PUS(16777216);
    float *dST_f = PF(17825792), *delta_f = PF(26214400), *BtCt_f = PF(28311552);
    ushort_t *Wg1T0 = PUS(28573696), *Wg1T1 = PUS(28868608);
    ushort_t *Wf1T = PUS(29163520), *Wf2T = PUS(29687808);
    ushort_t *WxdT0 = PUS(30212096), *WxdT1 = PUS(30343168);
    ushort_t *WvT0 = PUS(30474240), *WvT1 = PUS(30605312);
    ushort_t *WoT0 = PUS(30736384), *WoT1 = PUS(30867456);
    ushort_t *Wg2T0 = PUS(30998528), *Wg2T1 = PUS(31129600);
    ushort_t *WdtT0 = PUS(31260672), *WdtT1 = PUS(31293440);
    ushort_t *WxpP0 = PUS(31326208), *WxpP1 = PUS(31358976);
    ushort_t *WbcT0 = PUS(31391744), *WbcT1 = PUS(31424512);
    float *mbuf = PF(31457280), *dzc = PF(31465472);
    ushort_t *gatein_hi = PUS(31498240), *gatein_lo = PUS(33857536);
    ushort_t *ST_lo = PUS(36216832);
    float *scores_f = PF(40411136);
    ushort_t *scores_hi = PUS(41459712), *scores_lo = PUS(41984000);
    ushort_t *omT0 = PUS(17825792), *omT1 = PUS(17956864), *omT2 = PUS(18087936);
    ushort_t *Wq0 = PUS(18219008), *Wq1 = PUS(18350080), *Wq2 = PUS(18481152);
    ushort_t *Wk0 = PUS(18612224), *Wk1 = PUS(18743296), *Wk2 = PUS(18874368);
    ushort_t *WqoT0 = PUS(19005440), *WqoT1 = PUS(19136512), *WqoT2 = PUS(19267584);
    ushort_t *WkoT0 = PUS(19398656), *WkoT1 = PUS(19529728), *WkoT2 = PUS(19660800);
    ushort_t *ST_hi = PUS(11534336);
    float *hend = PF(0), *Pst = PF(524288), *hstart = PF(1048576);
    float *numA_f = PF(17825792), *numB_f = PF(19922944);
    ushort_t *g1_hi = PUS(22020096), *g1_lo = PUS(23068672);
    float *gbuf_f = PF(24117248);
    ushort_t *ypre_hi = PUS(7340032), *ypre_lo = PUS(8388608);
    float *hbuf_f = PF(11534336);
    ushort_t *hbuf_b = PUS(13631488);
    ushort_t *ffn1_b = PUS(3145728);
    float *ffn2_f = PF(15728640);

    // ---------------- P0: convert + norms ----------------
    for (int v = bid; v < 6912; v += NB) {
        if (v >= 6400) {
            int w = tid >> 6, lane = tid & 63;
            int token = (v - 6400) * 4 + w;
            const float4 vv = ((const float4*)(A.x + (long)token * 256))[lane];
            float s = vv.x * vv.x + vv.y * vv.y + vv.z * vv.z + vv.w * vv.w;
            #pragma unroll
            for (int msk = 32; msk; msk >>= 1) s += __shfl_xor(s, msk, 64);
            if (lane == 0) mbuf[token] = sqrtf(s);
            continue;
        }
        int i = v * 256 + tid;
        if (i < 524288) { split3(A.x[i], x0[i], x1[i], x2[i]); continue; }
        i -= 524288;
        if (i < 65536) { int r = i >> 8, c = i & 255; split3(A.omega[c * 256 + r], omT0[i], omT1[i], omT2[i]); continue; }
        i -= 65536;
        if (i < 65536) { split3(A.Wq[i], Wq0[i], Wq1[i], Wq2[i]); continue; }
        i -= 65536;
        if (i < 65536) { split3(A.Wk[i], Wk0[i], Wk1[i], Wk2[i]); continue; }
        i -= 65536;
        if (i < 65536) { int r = i >> 8, c = i & 255; split2(A.Wv[c * 256 + r], WvT0[i], WvT1[i]); continue; }
        i -= 65536;
        if (i < 65536) { int r = i >> 8, c = i & 255; split2(A.Wo[c * 256 + r], WoT0[i], WoT1[i]); continue; }
        i -= 65536;
        if (i < 147456) { int r = i / 576, c = i - r * 576;
                          float vv = (c < 513) ? A.Wg1[c * 256 + r] : 0.f;
                          split2(vv, Wg1T0[i], Wg1T1[i]); continue; }
        i -= 147456;
        if (i < 65536) { int r = i >> 8, c = i & 255; split2(A.Wg2[c * 256 + r], Wg2T0[i], Wg2T1[i]); continue; }
        i -= 65536;
        if (i < 262144) { int r = i >> 8, c = i & 255; Wf1T[i] = f2b(A.Wf1[c * 1024 + r]); continue; }
        i -= 262144;
        if (i < 262144) { int r = i >> 10, c = i & 1023; Wf2T[i] = f2b(A.Wf2[c * 256 + r]); continue; }
        i -= 262144;
        if (i < 16384) { int m = i >> 6, k = i & 63;
                         float vv = (k < 16) ? A.Wdt[k * 256 + m] : 0.f;
                         split2(vv, WdtT0[i], WdtT1[i]); continue; }
        i -= 16384;
        if (i < 16384) { int n = i >> 6, k = i & 63;
                         float vv = (k < 16) ? A.Wxp[n * 32 + k] : 0.f;
                         split2(vv, WxpP0[i], WxpP1[i]); continue; }
        i -= 16384;
        if (i < 16384) { int r = i >> 8, c = i & 255;
                         float vv = (r < 16) ? A.Wxp[c * 32 + 16 + r] : ((r < 32) ? A.Wc[c * 16 + (r - 16)] : 0.f);
                         split2(vv, WbcT0[i], WbcT1[i]); continue; }
    }
    grid.sync();

    // ---------------- P1: {Wqo, Wko, Wxd} (48) ----------------
    {
        GJob a{}; a.A0=omT0; a.A1=omT1; a.A2=omT2; a.B0=Wq0; a.B1=Wq1; a.B2=Wq2;
        a.o0=WqoT0; a.o1=WqoT1; a.o2=WqoT2; a.lda=256; a.ldb=256; a.ldob=256;
        a.act=ACT_NONE; a.ns=3; a.K=256; a.N=256; a.nx=4; a.ny=4; a.base=0; a.zmod=1;
        GJob b = a; b.B0=Wk0; b.B1=Wk1; b.B2=Wk2; b.o0=WkoT0; b.o1=WkoT1; b.o2=WkoT2; b.base=16;
        GJob c{}; c.A0=WdtT0; c.A1=WdtT1; c.B0=WxpP0; c.B1=WxpP1;
        c.o0=WxdT0; c.o1=WxdT1; c.lda=64; c.ldb=64; c.ldob=256;
        c.act=ACT_NONE; c.ns=2; c.K=64; c.N=256; c.nx=4; c.ny=4; c.base=32; c.zmod=1;
        GJob js[3] = {a, b, c};
        for (int v = bid; v < 48; v += NB) gemm_body<3>(v, js, 3, ldsbuf);
    }
    grid.sync();

    // ---------------- P2: {V->VT, Qp, Kp(+KpT), BtCt, delta} (544) ----------------
    {
        GJob v{}; v.A0=x0; v.A1=x1; v.B0=WvT0; v.B1=WvT1;
        v.t0=VT_hi; v.t1=VT_lo; v.sTb=262144;
        v.lda=256; v.ldb=256; v.act=ACT_NONE; v.ns=2; v.K=256; v.N=256;
        v.nx=4; v.ny=32; v.base=0; v.zmod=1;
        GJob q{}; q.A0=x0; q.A1=x1; q.A2=x2; q.B0=WqoT0; q.B1=WqoT1; q.B2=WqoT2;
        q.o0=Qp_hi; q.o1=Qp_lo; q.lda=256; q.ldb=256; q.ldob=512;
        q.act=ACT_RFF; q.ns=3; q.K=256; q.N=256; q.nx=4; q.ny=32; q.base=128; q.zmod=1;
        GJob k = q; k.B0=WkoT0; k.B1=WkoT1; k.B2=WkoT2; k.o0=Kp_hi; k.o1=Kp_lo;
        k.t0=KpT_hi; k.t1=KpT_lo; k.sTb=524288; k.base=256;
        GJob bc{}; bc.A0=x0; bc.A1=x1; bc.B0=WbcT0; bc.B1=WbcT1;
        bc.outF=BtCt_f; bc.lda=256; bc.ldb=256; bc.ldo=32;
        bc.act=ACT_NONE; bc.ns=2; bc.K=256; bc.N=32; bc.nx=1; bc.ny=32; bc.base=384; bc.zmod=1;
        GJob dl{}; dl.A0=x0; dl.A1=x1; dl.B0=WxdT0; dl.B1=WxdT1; dl.bias=A.b_dt;
        dl.outF=delta_f; dl.lda=256; dl.ldb=256; dl.ldo=256;
        dl.act=ACT_SOFTPLUS; dl.ns=2; dl.K=256; dl.N=256; dl.nx=4; dl.ny=32; dl.base=416; dl.zmod=1;
        GJob js[5] = {v, q, k, bc, dl};
        for (int vb = bid; vb < 544; vb += NB) gemm_body<3>(vb, js, 5, ldsbuf);
    }
    grid.sync();

    // ---------------- P3: {dST, scores} + SSM pass-1 (1088) ----------------
    {
        GJob d{}; d.A0=VT_hi; d.A1=VT_lo; d.B0=KpT_hi; d.B1=KpT_lo;
        d.outF=dST_f; d.lda=1024; d.ldb=1024; d.ldo=512;
        d.act=ACT_NONE; d.ns=2; d.K=128; d.N=512; d.nx=8; d.ny=4; d.base=0; d.zmod=8;
        d.sAb1=262144; d.sAb2=128; d.sBb1=524288; d.sBb2=128; d.sOb=131072;
        GJob s{}; s.A0=Qp_hi; s.A1=Qp_lo; s.B0=Kp_hi; s.B1=Kp_lo;
        s.outF=scores_f; s.o0=scores_hi; s.o1=scores_lo;
        s.lda=512; s.ldb=512; s.ldo=128; s.ldob=128;
        s.act=ACT_CAUSAL; s.ns=2; s.K=512; s.N=128; s.nx=2; s.ny=2; s.base=512; s.zmod=1;
        s.sAb1=65536; s.sBb1=65536; s.sOb=16384; s.sObB=16384;
        GJob js[2] = {d, s};
        for (int vb = bid; vb < 1088; vb += NB) {
            if (vb >= 576)
                ssm_body<1>(vb - 576, A.x, delta_f, BtCt_f, A.A_log, hend, Pst,
                            nullptr, nullptr, nullptr, ldsbuf);
            else
                gemm_body<2>(vb, js, 2, ldsbuf);
        }
    }
    grid.sync();

    // ---------------- P4: scan mix (1088) ----------------
    for (int gb = bid; gb < 1088; gb += NB) {
        if (gb < 32) {
            int t = gb * 256 + tid;
            int b = t >> 12;
            int dn = t & 4095;
            float hs = 0.f;
            for (int c = 0; c < 16; ++c) {
                long idx = ((long)(b * 16 + c) << 12) + dn;
                hstart[idx] = hs;
                hs = Pst[idx] * hs + hend[idx];
            }
        } else if (gb < 64) {
            int idx = (gb - 32) * 256 + tid;
            int bc = idx >> 9, f = idx & 511;
            float s = 0.f;
            for (int t = 0; t < 128; ++t) {
                long i = ((long)bc * 128 + t) * 512 + f;
                s += b2f(Kp_hi[i]) + b2f(Kp_lo[i]);
            }
            dzc[(long)bc * 512 + f] = s;
        } else {
            int t = (gb - 64) * 256 + tid;
            int b = t >> 17;
            int df = t & 131071;
            float acc = 0.f;
            for (int c = 0; c < 8; ++c) {
                long idx = (long)(b * 8 + c) * 131072 + df;
                float v = dST_f[idx];
                ushort_t h = f2b(acc);
                ST_hi[idx] = h;
                ST_lo[idx] = f2b(acc - b2f(h));
                acc += v;
            }
        }
    }
    grid.sync();

    // ---------------- P5: {numA, numB} + SSM pass-3 (768) ----------------
    {
        GJob a{}; a.A0=scores_hi; a.A1=scores_lo; a.B0=VT_hi; a.B1=VT_lo;
        a.outF=numA_f; a.lda=128; a.ldb=1024; a.ldo=256;
        a.act=ACT_NONE; a.ns=2; a.K=128; a.N=256; a.nx=4; a.ny=2; a.base=0; a.zmod=8;
        a.sAb1=131072; a.sAb2=16384; a.sBb1=262144; a.sBb2=128; a.sOb=32768;
        GJob b{}; b.A0=Qp_hi; b.A1=Qp_lo; b.B0=ST_hi; b.B1=ST_lo;
        b.outF=numB_f; b.lda=512; b.ldb=512; b.ldo=256;
        b.act=ACT_NONE; b.ns=2; b.K=512; b.N=256; b.nx=4; b.ny=2; b.base=128; b.zmod=1;
        b.sAb1=65536; b.sBb1=131072; b.sOb=32768;
        GJob js[2] = {a, b};
        for (int vb = bid; vb < 768; vb += NB) {
            if (vb >= 256)
                ssm_body<3>(vb - 256, A.x, delta_f, BtCt_f, A.A_log, nullptr, nullptr,
                            hstart, gatein_hi, gatein_lo, ldsbuf);
            else
                gemm_body<2>(vb, js, 2, ldsbuf);
        }
    }
    grid.sync();

    // ---------------- P6: attn_finish (512 x 4 tokens) ----------------
    for (int v = bid; v < 512; v += NB) {
        int w = tid >> 6, lane = tid & 63;
        int token = v * 4 + w;
        int b = token >> 10, tloc = token & 1023;
        int c = tloc >> 7, tin = tloc & 127;
        int bc = b * 8 + c;
        const float* srow = scores_f + ((long)bc * 128 + tin) * 128;
        float s = srow[lane] + srow[lane + 64];
        const ushort_t* qh = Qp_hi + (long)token * 512;
        const ushort_t* ql = Qp_lo + (long)token * 512;
        float q[8];
        #pragma unroll
        for (int j = 0; j < 8; ++j) {
            int f = lane + 64 * j;
            q[j] = b2f(qh[f]) + b2f(ql[f]);
        }
        for (int c2 = 0; c2 < c; ++c2) {
            const float* z = dzc + (long)(b * 8 + c2) * 512;
            #pragma unroll
            for (int j = 0; j < 8; ++j) s += q[j] * z[lane + 64 * j];
        }
        #pragma unroll
        for (int m = 32; m; m >>= 1) s += __shfl_xor(s, m, 64);
        float inv = 1.f / (s + 1e-6f);
        const float* na = numA_f + (long)token * 256;
        const float* nb = numB_f + (long)token * 256;
        #pragma unroll
        for (int j = 0; j < 4; ++j) {
            int idx = lane + 64 * j;
            float vv = (na[idx] + nb[idx]) * inv;
            ushort_t h = f2b(vv);
            ypre_hi[(long)token * 256 + idx] = h;
            ypre_lo[(long)token * 256 + idx] = f2b(vv - b2f(h));
        }
        if (lane == 0) {
            float wv[8];
            #pragma unroll
            for (int i = 0; i < 8; ++i) {
                int idx = tloc - 7 + i;
                wv[i] = (idx >= 0) ? mbuf[b * 1024 + idx] : -1e30f;
            }
            float mx = wv[0];
            #pragma unroll
            for (int i = 1; i < 8; ++i) mx = fmaxf(mx, wv[i]);
            float e[8], sum = 0.f;
            #pragma unroll
            for (int i = 0; i < 8; ++i) { e[i] = __expf(wv[i] - mx); sum += e[i]; }
            float invs = 1.f / sum, Hv = 0.f;
            #pragma unroll
            for (int i = 0; i < 8; ++i) {
                float p = e[i] * invs;
                Hv -= p * __logf(p + 1e-9f);
            }
            float H = Hv * 1.4426950408889634f;
            ushort_t hh = f2b(H);
            gatein_hi[(long)token * 576 + 512] = hh;
            gatein_lo[(long)token * 576 + 512] = f2b(H - b2f(hh));
        }
        if (lane < 63) {
            gatein_hi[(long)token * 576 + 513 + lane] = 0;
            gatein_lo[(long)token * 576 + 513 + lane] = 0;
        }
    }
    grid.sync();

    // ---------------- P7: yattn = ypre@Wo (128) ----------------
    {
        GJob w{}; w.A0=ypre_hi; w.A1=ypre_lo; w.B0=WoT0; w.B1=WoT1;
        w.o0=gatein_hi; w.o1=gatein_lo; w.colOffB=256;
        w.lda=256; w.ldb=256; w.ldob=576;
        w.act=ACT_NONE; w.ns=2; w.K=256; w.N=256; w.nx=4; w.ny=32; w.base=0; w.zmod=1;
        GJob js[1] = {w};
        for (int v = bid; v < 128; v += NB) gemm_body<2>(v, js, 1, ldsbuf);
    }
    grid.sync();

    // ---------------- P8: g1 (128) ----------------
    {
        GJob g{}; g.A0=gatein_hi; g.A1=gatein_lo; g.B0=Wg1T0; g.B1=Wg1T1; g.bias=A.bg1;
        g.o0=g1_hi; g.o1=g1_lo; g.lda=576; g.ldb=576; g.ldob=256;
        g.act=ACT_SILU; g.ns=2; g.K=576; g.N=256; g.nx=4; g.ny=32; g.base=0; g.zmod=1;
        GJob js[1] = {g};
        for (int v = bid; v < 128; v += NB) gemm_body<2>(v, js, 1, ldsbuf);
    }
    grid.sync();

    // ---------------- P9: g2 (128) ----------------
    {
        GJob g{}; g.A0=g1_hi; g.A1=g1_lo; g.B0=Wg2T0; g.B1=Wg2T1; g.bias=A.bg2;
        g.outF=gbuf_f; g.lda=256; g.ldb=256; g.ldo=256;
        g.act=ACT_SIGMOID; g.ns=2; g.K=256; g.N=256; g.nx=4; g.ny=32; g.base=0; g.zmod=1;
        GJob js[1] = {g};
        for (int v = bid; v < 128; v += NB) gemm_body<2>(v, js, 1, ldsbuf);
    }
    grid.sync();

    // ---------------- P10: ln1 (2048) ----------------
    for (int t = bid; t < 2048; t += NB) {
        float* red = (float*)ldsbuf;
        long idx = (long)t * 256 + tid;
        float yssm  = b2f(gatein_hi[(long)t * 576 + tid])       + b2f(gatein_lo[(long)t * 576 + tid]);
        float yattn = b2f(gatein_hi[(long)t * 576 + 256 + tid]) + b2f(gatein_lo[(long)t * 576 + 256 + tid]);
        float gv = gbuf_f[idx];
        float v = A.x[idx] + gv * yssm + (1.f - gv) * yattn;
        float s = v;
        #pragma unroll
        for (int m = 32; m; m >>= 1) s += __shfl_xor(s, m, 64);
        if ((tid & 63) == 0) red[tid >> 6] = s;
        __syncthreads();
        float mu = (red[0] + red[1] + red[2] + red[3]) * (1.f / 256.f);
        float dv = v - mu;
        float s2 = dv * dv;
        #pragma unroll
        for (int m = 32; m; m >>= 1) s2 += __shfl_xor(s2, m, 64);
        if ((tid & 63) == 0) red[4 + (tid >> 6)] = s2;
        __syncthreads();
        float var = (red[4] + red[5] + red[6] + red[7]) * (1.f / 256.f);
        float o = dv * rsqrtf(var + 1e-5f) * A.ln1g[tid] + A.ln1b[tid];
        hbuf_f[idx] = o;
        hbuf_b[idx] = f2b(o);
        __syncthreads();
    }
    grid.sync();

    // ---------------- P11: FFN1 (512) ----------------
    {
        GJob f{}; f.A0=hbuf_b; f.B0=Wf1T; f.bias=A.bf1;
        f.o0=ffn1_b; f.lda=256; f.ldb=256; f.ldob=1024;
        f.act=ACT_GELU; f.ns=1; f.K=256; f.N=1024; f.nx=16; f.ny=32; f.base=0; f.zmod=1;
        GJob js[1] = {f};
        for (int v = bid; v < 512; v += NB) gemm_body<1>(v, js, 1, ldsbuf);
    }
    grid.sync();

    // ---------------- P12: FFN2 (128) ----------------
    {
        GJob f{}; f.A0=ffn1_b; f.B0=Wf2T; f.bias=A.bf2;
        f.outF=ffn2_f; f.lda=1024; f.ldb=1024; f.ldo=256;
        f.act=ACT_NONE; f.ns=1; f.K=1024; f.N=256; f.nx=4; f.ny=32; f.base=0; f.zmod=1;
        GJob js[1] = {f};
        for (int v = bid; v < 128; v += NB) gemm_body<1>(v, js, 1, ldsbuf);
    }
    grid.sync();

    // ---------------- P13: ln2 (2048) ----------------
    for (int t = bid; t < 2048; t += NB) {
        float* red = (float*)ldsbuf;
        long idx = (long)t * 256 + tid;
        float v = hbuf_f[idx] + ffn2_f[idx];
        float s = v;
        #pragma unroll
        for (int m = 32; m; m >>= 1) s += __shfl_xor(s, m, 64);
        if ((tid & 63) == 0) red[tid >> 6] = s;
        __syncthreads();
        float mu = (red[0] + red[1] + red[2] + red[3]) * (1.f / 256.f);
        float dv = v - mu;
        float s2 = dv * dv;
        #pragma unroll
        for (int m = 32; m; m >>= 1) s2 += __shfl_xor(s2, m, 64);
        if ((tid & 63) == 0) red[4 + (tid >> 6)] = s2;
        __syncthreads();
        float var = (red[4] + red[5] + red[6] + red[7]) * (1.f / 256.f);
        A.out[idx] = dv * rsqrtf(var + 1e-5f) * A.ln2g[tid] + A.ln2b[tid];
        __syncthreads();
    }
}

// ---------------------------------------------------------------------------

extern "C" void kernel_launch(void* const* d_in, const int* in_sizes, int n_in,
                              void* d_out, int out_size, void* d_ws, size_t ws_size,
                              hipStream_t stream)
{
    if (ws_size < (size_t)42778624) return;

    MegaArgs A;
    A.x     = (const float*)d_in[0];
    A.A_log = (const float*)d_in[1];
    A.Wxp   = (const float*)d_in[2];
    A.Wdt   = (const float*)d_in[3];
    A.b_dt  = (const float*)d_in[4];
    A.Wc    = (const float*)d_in[5];
    A.Wq    = (const float*)d_in[6];
    A.Wk    = (const float*)d_in[7];
    A.Wv    = (const float*)d_in[8];
    A.Wo    = (const float*)d_in[9];
    A.omega = (const float*)d_in[10];
    A.Wg1   = (const float*)d_in[11];
    A.bg1   = (const float*)d_in[12];
    A.Wg2   = (const float*)d_in[13];
    A.bg2   = (const float*)d_in[14];
    A.ln1g  = (const float*)d_in[15];
    A.ln1b  = (const float*)d_in[16];
    A.ln2g  = (const float*)d_in[17];
    A.ln2b  = (const float*)d_in[18];
    A.Wf1   = (const float*)d_in[19];
    A.bf1   = (const float*)d_in[20];
    A.Wf2   = (const float*)d_in[21];
    A.bf2   = (const float*)d_in[22];
    A.B     = (char*)d_ws;
    A.out   = (float*)d_out;

    // Size the cooperative grid from the occupancy query (deterministic,
    // capture-safe).  55 KB static LDS -> at most 2 blocks/CU; fall back to
    // 1 block/CU (256 blocks) which always satisfies co-residency.
    int perCU = 0;
    hipError_t qe = hipOccupancyMaxActiveBlocksPerMultiprocessor(
        &perCU, (const void*)mega, 256, 0);
    int grid = (qe == hipSuccess && perCU >= 2) ? 512 : 256;

    void* kargs[] = { &A };
    hipError_t le = hipLaunchCooperativeKernel((const void*)mega, dim3(grid),
                                               dim3(256), kargs, 0, stream);
    if (le != hipSuccess && grid != 256) {
        hipLaunchCooperativeKernel((const void*)mega, dim3(256),
                                   dim3(256), kargs, 0, stream);
    }
}

// Round 14
// 310.018 us; speedup vs baseline: 2.7236x; 2.7236x over previous
//
#include <hip/hip_runtime.h>
#include <math.h>

typedef unsigned short ushort_t;
typedef unsigned int uint_t;
typedef __attribute__((ext_vector_type(8))) short short8;
typedef __attribute__((ext_vector_type(4))) float f32x4;

#define ACT_NONE     0
#define ACT_SOFTPLUS 1
#define ACT_SILU     2
#define ACT_SIGMOID  3
#define ACT_GELU     4
#define ACT_RFF      5
#define ACT_CAUSAL   6

__device__ __forceinline__ ushort_t f2b(float f) {
    union { float f; uint_t u; } v; v.f = f;
    uint_t u = v.u;
    uint_t r = (u + 0x7FFFu + ((u >> 16) & 1u)) >> 16;
    return (ushort_t)r;
}
__device__ __forceinline__ float b2f(ushort_t h) {
    union { uint_t u; float f; } v; v.u = ((uint_t)h) << 16;
    return v.f;
}
__device__ __forceinline__ void split2(float v, ushort_t& h0, ushort_t& h1) {
    h0 = f2b(v); h1 = f2b(v - b2f(h0));
}
__device__ __forceinline__ void split3(float v, ushort_t& h0, ushort_t& h1, ushort_t& h2) {
    h0 = f2b(v); float r1 = v - b2f(h0);
    h1 = f2b(r1); h2 = f2b(r1 - b2f(h1));
}

// fast erf: Abramowitz-Stegun 7.1.26, max abs error 1.5e-7
__device__ __forceinline__ float fast_erf(float x) {
    float ax = fabsf(x);
    float t = 1.f / (1.f + 0.3275911f * ax);
    float poly = t * (0.254829592f + t * (-0.284496736f + t * (1.421413741f
               + t * (-1.453152027f + t * 1.061405429f))));
    float er = 1.f - poly * __expf(-ax * ax);
    return copysignf(er, x);
}

__device__ __forceinline__ float act_apply(float v, int act) {
    switch (act) {
        case ACT_SOFTPLUS: return v > 0.f ? v + __logf(1.f + __expf(-v)) : __logf(1.f + __expf(v));
        case ACT_SILU:     return v / (1.f + __expf(-v));
        case ACT_SIGMOID:  return 1.f / (1.f + __expf(-v));
        case ACT_GELU:     return 0.5f * v * (1.f + fast_erf(v * 0.7071067811865475f));
        default:           return v;
    }
}

// ---------------------------------------------------------------------------
// Multi-job MFMA GEMM with optional SSM-pass aux blocks (AUXPASS=1 or 3).
// All operands row-major [row][K].  ns-term bf16 splits.  Jobs packed along
// linear blockIdx.x; aux blocks start at S.base.
// ---------------------------------------------------------------------------
#define LDK2 72     // 64 data + 8 pad ushorts -> 144B rows (16B aligned)
#define TSTRIDE 66  // transpose-staging tile stride

struct GJob {
    const ushort_t *A0, *A1, *A2, *B0, *B1, *B2;
    const float* bias;
    float* outF;
    ushort_t *o0, *o1, *o2, *t0, *t1;
    int lda, ldb, ldo, ldob, colOffB, act, ns, K, N;
    int nx, ny, base, zmod;
    int sAb1, sAb2, sBb1, sBb2, sOb, sObB, sTb;
};

struct SJob {
    const float *x, *delta, *BtCt, *A_log, *hstart;
    float *hend, *Pst;
    ushort_t *giH, *giL;
    int base;
};

template<int NSMAX, int AUXPASS>
__global__ __launch_bounds__(256)
void gemm_multi(GJob J0, GJob J1, GJob J2, GJob J3, GJob J4, SJob S)
{
    __shared__ ushort_t ldsbuf[NSMAX * 2 * 64 * LDK2];
    ushort_t (*sA)[64 * LDK2] = (ushort_t(*)[64 * LDK2])ldsbuf;
    ushort_t (*sB)[64 * LDK2] = (ushort_t(*)[64 * LDK2])(ldsbuf + NSMAX * 64 * LDK2);

    int bid = blockIdx.x;

    if constexpr (AUXPASS != 0) {
        if (bid >= S.base) {
            // ---- SSM chunked scan pass (1: local+decay, 3: replay+emit) ----
            const int bx2 = bid - S.base;
            const int dblk = bx2 & 15, cc = (bx2 >> 4) & 15, bb2 = bx2 >> 8;
            const int tid2 = threadIdx.x;
            const int nn = tid2 & 15, dl = tid2 >> 4;
            const int dd = dblk * 16 + dl;
            float* sd  = (float*)ldsbuf;        // [64][16]
            float* sx2 = sd + 1024;
            float* sB2 = sx2 + 1024;
            float* sC2 = sB2 + 1024;
            #pragma unroll
            for (int it = 0; it < 4; ++it) {
                int i2 = it * 256 + tid2;
                int t2 = i2 >> 4, j2 = i2 & 15;
                long row = (long)bb2 * 1024 + cc * 64 + t2;
                sd[t2 * 16 + j2]  = S.delta[row * 256 + dblk * 16 + j2];
                sx2[t2 * 16 + j2] = S.x[row * 256 + dblk * 16 + j2];
                sB2[t2 * 16 + j2] = S.BtCt[row * 32 + j2];
                if (AUXPASS == 3) sC2[t2 * 16 + j2] = S.BtCt[row * 32 + 16 + j2];
            }
            __syncthreads();
            const float acoef = -__expf(S.A_log[dd * 16 + nn]);
            float h = 0.f, P = 1.f;
            if (AUXPASS == 3) h = S.hstart[((long)(bb2 * 16 + cc) << 12) + dd * 16 + nn];
            for (int t2 = 0; t2 < 64; ++t2) {
                float dlt = sd[t2 * 16 + dl];
                float a2 = __expf(dlt * acoef);
                h = a2 * h + (dlt * sx2[t2 * 16 + dl]) * sB2[t2 * 16 + nn];
                if (AUXPASS == 1) P *= a2;
                if (AUXPASS == 3) {
                    float part = sC2[t2 * 16 + nn] * h;
                    #pragma unroll
                    for (int msk = 8; msk; msk >>= 1) part += __shfl_xor(part, msk, 16);
                    if (nn == 0) {
                        long row = (long)bb2 * 1024 + cc * 64 + t2;
                        ushort_t hh = f2b(part);
                        S.giH[row * 576 + dd] = hh;
                        S.giL[row * 576 + dd] = f2b(part - b2f(hh));
                    }
                }
            }
            if (AUXPASS == 1) {
                long idx = ((long)(bb2 * 16 + cc) << 12) + dd * 16 + nn;
                S.hend[idx] = h;
                S.Pst[idx] = P;
            }
            return;
        }
    }

    GJob J = J0;
    if (J4.nx && bid >= J4.base) J = J4;
    else if (J3.nx && bid >= J3.base) J = J3;
    else if (J2.nx && bid >= J2.base) J = J2;
    else if (J1.nx && bid >= J1.base) J = J1;

    int rel = bid - J.base;
    int perz = J.nx * J.ny;
    int bz = rel / perz; rel -= bz * perz;
    int by = rel / J.nx, bx = rel - by * J.nx;
    int zq = bz / J.zmod, zr = bz - zq * J.zmod;

    const ushort_t* As[3] = {J.A0, J.A1, J.A2};
    const ushort_t* Bs[3] = {J.B0, J.B1, J.B2};
    long offA = (long)zq * J.sAb1 + (long)zr * J.sAb2;
    long offB = (long)zq * J.sBb1 + (long)zr * J.sBb2;
    #pragma unroll
    for (int s = 0; s < NSMAX; ++s) { As[s] += offA; Bs[s] += offB; }
    float* outF = J.outF ? J.outF + (long)bz * J.sOb : nullptr;
    ushort_t* o0 = J.o0 ? J.o0 + (long)bz * J.sObB : nullptr;
    ushort_t* o1 = J.o1 ? J.o1 + (long)bz * J.sObB : nullptr;
    ushort_t* o2 = J.o2 ? J.o2 + (long)bz * J.sObB : nullptr;

    const int m0 = by * 64, n0 = bx * 64;
    const int tid = threadIdx.x, lane = tid & 63, wid = tid >> 6;
    const int wr = (wid >> 1) * 32, wc = (wid & 1) * 32;
    const int lr = lane & 15, lk = (lane >> 4) * 8;
    const int rS = tid >> 3, c8 = (tid & 7) * 8;

    uint4 rA[NSMAX][2], rB[NSMAX][2];

    auto LOAD = [&](int k0) {
        #pragma unroll
        for (int s = 0; s < NSMAX; ++s) if (s < J.ns) {
            #pragma unroll
            for (int p = 0; p < 2; ++p) {
                rA[s][p] = *(const uint4*)(As[s] + (long)(m0 + rS + 32 * p) * J.lda + k0 + c8);
                rB[s][p] = *(const uint4*)(Bs[s] + (long)(n0 + rS + 32 * p) * J.ldb + k0 + c8);
            }
        }
    };
    auto STORE = [&]() {
        #pragma unroll
        for (int s = 0; s < NSMAX; ++s) if (s < J.ns) {
            #pragma unroll
            for (int p = 0; p < 2; ++p) {
                *(uint4*)&sA[s][(rS + 32 * p) * LDK2 + c8] = rA[s][p];
                *(uint4*)&sB[s][(rS + 32 * p) * LDK2 + c8] = rB[s][p];
            }
        }
    };

    f32x4 acc[2][2];
    #pragma unroll
    for (int i = 0; i < 2; ++i)
        #pragma unroll
        for (int j = 0; j < 2; ++j)
            acc[i][j] = (f32x4){0.f, 0.f, 0.f, 0.f};

    const int niter = J.K >> 6;
    LOAD(0);
    for (int it = 0; it < niter; ++it) {
        if (it) __syncthreads();
        STORE();
        __syncthreads();
        if (it + 1 < niter) LOAD((it + 1) << 6);
        #pragma unroll
        for (int ks = 0; ks < 2; ++ks) {
            short8 af[NSMAX][2], bg[NSMAX][2];
            #pragma unroll
            for (int s = 0; s < NSMAX; ++s) if (s < J.ns) {
                af[s][0] = *(const short8*)&sA[s][(wr + lr) * LDK2 + ks * 32 + lk];
                af[s][1] = *(const short8*)&sA[s][(wr + 16 + lr) * LDK2 + ks * 32 + lk];
                bg[s][0] = *(const short8*)&sB[s][(wc + lr) * LDK2 + ks * 32 + lk];
                bg[s][1] = *(const short8*)&sB[s][(wc + 16 + lr) * LDK2 + ks * 32 + lk];
            }
            #pragma unroll
            for (int i = 0; i < 2; ++i) {
                #pragma unroll
                for (int j = 0; j < 2; ++j) {
                    acc[i][j] = __builtin_amdgcn_mfma_f32_16x16x32_bf16(af[0][i], bg[0][j], acc[i][j], 0, 0, 0);
                    if constexpr (NSMAX >= 2) if (J.ns >= 2) {
                        acc[i][j] = __builtin_amdgcn_mfma_f32_16x16x32_bf16(af[0][i], bg[1][j], acc[i][j], 0, 0, 0);
                        acc[i][j] = __builtin_amdgcn_mfma_f32_16x16x32_bf16(af[1][i], bg[0][j], acc[i][j], 0, 0, 0);
                    }
                    if constexpr (NSMAX >= 3) if (J.ns >= 3) {
                        acc[i][j] = __builtin_amdgcn_mfma_f32_16x16x32_bf16(af[0][i], bg[2][j], acc[i][j], 0, 0, 0);
                        acc[i][j] = __builtin_amdgcn_mfma_f32_16x16x32_bf16(af[1][i], bg[1][j], acc[i][j], 0, 0, 0);
                        acc[i][j] = __builtin_amdgcn_mfma_f32_16x16x32_bf16(af[2][i], bg[0][j], acc[i][j], 0, 0, 0);
                    }
                }
            }
        }
    }

    // ---- epilogue ----
    ushort_t* sAf = &sA[0][0];
    ushort_t* sBf = &sB[0][0];
    const bool hasT = (J.t0 != nullptr);
    if (hasT) __syncthreads();

    #pragma unroll
    for (int i = 0; i < 2; ++i) {
        #pragma unroll
        for (int j = 0; j < 2; ++j) {
            #pragma unroll
            for (int rr = 0; rr < 4; ++rr) {
                int rl2 = wr + i * 16 + (lane >> 4) * 4 + rr;
                int cl2 = wc + j * 16 + lr;
                int row = m0 + rl2;
                int col = n0 + cl2;
                if (col >= J.N) continue;
                float v = acc[i][j][rr];
                if (J.bias) v += J.bias[col];
                if (J.act == ACT_RFF) {
                    const float sc = 0.08838834764831845f;
                    float sv_, cv_;
                    __sincosf(v, &sv_, &cv_);
                    float cv = sc * cv_, sv = sc * sv_;
                    ushort_t ch = f2b(cv), sh = f2b(sv);
                    ushort_t cL = f2b(cv - b2f(ch)), sL = f2b(sv - b2f(sh));
                    long oc = (long)row * J.ldob + col, os = oc + J.N;
                    o0[oc] = ch; o0[os] = sh;
                    o1[oc] = cL; o1[os] = sL;
                    if (hasT) {
                        sAf[cl2 * TSTRIDE + rl2] = ch;
                        sAf[4224 + cl2 * TSTRIDE + rl2] = cL;
                        sBf[cl2 * TSTRIDE + rl2] = sh;
                        sBf[4224 + cl2 * TSTRIDE + rl2] = sL;
                    }
                    continue;
                }
                if (J.act == ACT_CAUSAL) { if (col > row) v = 0.f; }
                else v = act_apply(v, J.act);
                if (outF) outF[(long)row * J.ldo + col] = v;
                if (o0) {
                    long o = (long)row * J.ldob + J.colOffB + col;
                    ushort_t h0 = f2b(v); o0[o] = h0;
                    if (o1) {
                        float r1 = v - b2f(h0);
                        ushort_t h1 = f2b(r1); o1[o] = h1;
                        if (o2) o2[o] = f2b(r1 - b2f(h1));
                    }
                }
                if (hasT) {
                    ushort_t h0 = f2b(v);
                    sAf[cl2 * TSTRIDE + rl2] = h0;
                    sAf[4224 + cl2 * TSTRIDE + rl2] = f2b(v - b2f(h0));
                }
            }
        }
    }

    if (hasT) {
        __syncthreads();
        int bb = m0 >> 10, tl0 = m0 & 1023;
        int cl = tid >> 2, seg = tid & 3;
        int ngroups = (J.act == ACT_RFF) ? 2 : 1;
        for (int g = 0; g < ngroups; ++g) {
            const ushort_t* th = (g ? sBf : sAf) + cl * TSTRIDE + seg * 16;
            const ushort_t* tl = th + 4224;
            long gcol = (long)(n0 + cl) + (long)g * J.N;
            long addr = (long)bb * J.sTb + gcol * 1024 + tl0 + seg * 16;
            uint_t wh[8], wl[8];
            #pragma unroll
            for (int k2 = 0; k2 < 8; ++k2) {
                wh[k2] = (uint_t)th[2 * k2] | ((uint_t)th[2 * k2 + 1] << 16);
                wl[k2] = (uint_t)tl[2 * k2] | ((uint_t)tl[2 * k2 + 1] << 16);
            }
            *(uint4*)(J.t0 + addr)     = *(uint4*)&wh[0];
            *(uint4*)(J.t0 + addr + 8) = *(uint4*)&wh[4];
            *(uint4*)(J.t1 + addr)     = *(uint4*)&wl[0];
            *(uint4*)(J.t1 + addr + 8) = *(uint4*)&wl[4];
        }
    }
}

// ---------------------------------------------------------------------------
// Conversion (+ row norms folded at tail blocks).
// ---------------------------------------------------------------------------
#define CONV_BLKS 6400
__global__ __launch_bounds__(256)
void convert_kernel(const float* __restrict__ x, const float* __restrict__ Wxp,
                    const float* __restrict__ Wdt, const float* __restrict__ Wc,
                    const float* __restrict__ Wq, const float* __restrict__ Wk,
                    const float* __restrict__ Wv, const float* __restrict__ Wo,
                    const float* __restrict__ omega, const float* __restrict__ Wg1,
                    const float* __restrict__ Wg2, const float* __restrict__ Wf1,
                    const float* __restrict__ Wf2,
                    ushort_t* x0, ushort_t* x1, ushort_t* x2,
                    ushort_t* omT0, ushort_t* omT1, ushort_t* omT2,
                    ushort_t* Wq0, ushort_t* Wq1, ushort_t* Wq2,
                    ushort_t* Wk0, ushort_t* Wk1, ushort_t* Wk2,
                    ushort_t* WvT0, ushort_t* WvT1, ushort_t* WoT0, ushort_t* WoT1,
                    ushort_t* Wg1T0, ushort_t* Wg1T1, ushort_t* Wg2T0, ushort_t* Wg2T1,
                    ushort_t* Wf1T, ushort_t* Wf2T,
                    ushort_t* WdtT0, ushort_t* WdtT1, ushort_t* WxpP0, ushort_t* WxpP1,
                    ushort_t* WbcT0, ushort_t* WbcT1, float* mbuf)
{
    if (blockIdx.x >= CONV_BLKS) {   // row norms
        int w = threadIdx.x >> 6, lane = threadIdx.x & 63;
        int token = (blockIdx.x - CONV_BLKS) * 4 + w;
        const float4 v = ((const float4*)(x + (long)token * 256))[lane];
        float s = v.x * v.x + v.y * v.y + v.z * v.z + v.w * v.w;
        #pragma unroll
        for (int msk = 32; msk; msk >>= 1) s += __shfl_xor(s, msk, 64);
        if (lane == 0) mbuf[token] = sqrtf(s);
        return;
    }
    int i = blockIdx.x * 256 + threadIdx.x;
    if (i < 524288) { split3(x[i], x0[i], x1[i], x2[i]); return; }
    i -= 524288;
    if (i < 65536) { int r = i >> 8, c = i & 255; split3(omega[c * 256 + r], omT0[i], omT1[i], omT2[i]); return; }
    i -= 65536;
    if (i < 65536) { split3(Wq[i], Wq0[i], Wq1[i], Wq2[i]); return; }
    i -= 65536;
    if (i < 65536) { split3(Wk[i], Wk0[i], Wk1[i], Wk2[i]); return; }
    i -= 65536;
    if (i < 65536) { int r = i >> 8, c = i & 255; split2(Wv[c * 256 + r], WvT0[i], WvT1[i]); return; }
    i -= 65536;
    if (i < 65536) { int r = i >> 8, c = i & 255; split2(Wo[c * 256 + r], WoT0[i], WoT1[i]); return; }
    i -= 65536;
    if (i < 147456) { int r = i / 576, c = i - r * 576;
                      float v = (c < 513) ? Wg1[c * 256 + r] : 0.f;
                      split2(v, Wg1T0[i], Wg1T1[i]); return; }
    i -= 147456;
    if (i < 65536) { int r = i >> 8, c = i & 255; split2(Wg2[c * 256 + r], Wg2T0[i], Wg2T1[i]); return; }
    i -= 65536;
    if (i < 262144) { int r = i >> 8, c = i & 255; Wf1T[i] = f2b(Wf1[c * 1024 + r]); return; }
    i -= 262144;
    if (i < 262144) { int r = i >> 10, c = i & 1023; Wf2T[i] = f2b(Wf2[c * 256 + r]); return; }
    i -= 262144;
    if (i < 16384) { int m = i >> 6, k = i & 63;
                     float v = (k < 16) ? Wdt[k * 256 + m] : 0.f;
                     split2(v, WdtT0[i], WdtT1[i]); return; }
    i -= 16384;
    if (i < 16384) { int n = i >> 6, k = i & 63;
                     float v = (k < 16) ? Wxp[n * 32 + k] : 0.f;
                     split2(v, WxpP0[i], WxpP1[i]); return; }
    i -= 16384;
    if (i < 16384) { int r = i >> 8, c = i & 255;
                     float v = (r < 16) ? Wxp[c * 32 + 16 + r] : ((r < 32) ? Wc[c * 16 + (r - 16)] : 0.f);
                     split2(v, WbcT0[i], WbcT1[i]); return; }
}

// ---------------------------------------------------------------------------
// M2: blocks 0..31 SSM cross-chunk scan; 32..63 per-chunk K column sums;
// 64..1087 ST exclusive prefix (read-before-write ordering).
// ---------------------------------------------------------------------------
__global__ void scan_mix(const float* __restrict__ hend, const float* __restrict__ Pst,
                         float* __restrict__ hstart,
                         const ushort_t* __restrict__ Kh, const ushort_t* __restrict__ Kl,
                         float* __restrict__ dzc,
                         const float* __restrict__ dST,
                         ushort_t* __restrict__ STh, ushort_t* __restrict__ STl)
{
    int gb = blockIdx.x;
    if (gb < 32) {
        int tid = gb * 256 + threadIdx.x;
        int b = tid >> 12;
        int dn = tid & 4095;
        float hs = 0.f;
        for (int c = 0; c < 16; ++c) {
            long idx = ((long)(b * 16 + c) << 12) + dn;
            hstart[idx] = hs;
            hs = Pst[idx] * hs + hend[idx];
        }
    } else if (gb < 64) {
        int idx = (gb - 32) * 256 + threadIdx.x;   // 0..8191
        int bc = idx >> 9, f = idx & 511;
        float s = 0.f;
        for (int t = 0; t < 128; ++t) {
            long i = ((long)bc * 128 + t) * 512 + f;
            s += b2f(Kh[i]) + b2f(Kl[i]);
        }
        dzc[(long)bc * 512 + f] = s;
    } else {
        int t = (gb - 64) * 256 + threadIdx.x;     // 0..262143
        int b = t >> 17;
        int df = t & 131071;
        float acc = 0.f;
        for (int c = 0; c < 8; ++c) {
            long idx = (long)(b * 8 + c) * 131072 + df;
            float v = dST[idx];
            ushort_t h = f2b(acc);
            STh[idx] = h;
            STl[idx] = f2b(acc - b2f(h));
            acc += v;
        }
    }
}

// ---------------------------------------------------------------------------
// attn_finish: denominator + divide -> ypre 2-term; entropy + gatein pads.
// ---------------------------------------------------------------------------
__global__ void attn_finish(const float* __restrict__ scores,
                            const ushort_t* __restrict__ Qh, const ushort_t* __restrict__ Ql,
                            const float* __restrict__ dzc,
                            const float* __restrict__ numA, const float* __restrict__ numB,
                            const float* __restrict__ mbuf,
                            ushort_t* __restrict__ yh, ushort_t* __restrict__ yl,
                            ushort_t* __restrict__ giH, ushort_t* __restrict__ giL)
{
    int token = blockIdx.x;
    int b = token >> 10, tloc = token & 1023;
    int c = tloc >> 7, tin = tloc & 127;
    int bc = b * 8 + c;
    int lane = threadIdx.x;             // 64
    const float* srow = scores + ((long)bc * 128 + tin) * 128;
    float s = srow[lane] + srow[lane + 64];
    const ushort_t* qh = Qh + (long)token * 512;
    const ushort_t* ql = Ql + (long)token * 512;
    float q[8];
    #pragma unroll
    for (int j = 0; j < 8; ++j) {
        int f = lane + 64 * j;
        q[j] = b2f(qh[f]) + b2f(ql[f]);
    }
    for (int c2 = 0; c2 < c; ++c2) {
        const float* z = dzc + (long)(b * 8 + c2) * 512;
        #pragma unroll
        for (int j = 0; j < 8; ++j) s += q[j] * z[lane + 64 * j];
    }
    #pragma unroll
    for (int m = 32; m; m >>= 1) s += __shfl_xor(s, m, 64);
    float inv = 1.f / (s + 1e-6f);
    const float* na = numA + (long)token * 256;
    const float* nb = numB + (long)token * 256;
    #pragma unroll
    for (int j = 0; j < 4; ++j) {
        int idx = lane + 64 * j;
        float v = (na[idx] + nb[idx]) * inv;
        ushort_t h = f2b(v);
        yh[(long)token * 256 + idx] = h;
        yl[(long)token * 256 + idx] = f2b(v - b2f(h));
    }
    if (lane == 0) {
        float w[8];
        #pragma unroll
        for (int i = 0; i < 8; ++i) {
            int idx = tloc - 7 + i;
            w[i] = (idx >= 0) ? mbuf[b * 1024 + idx] : -1e30f;
        }
        float mx = w[0];
        #pragma unroll
        for (int i = 1; i < 8; ++i) mx = fmaxf(mx, w[i]);
        float e[8], sum = 0.f;
        #pragma unroll
        for (int i = 0; i < 8; ++i) { e[i] = __expf(w[i] - mx); sum += e[i]; }
        float invs = 1.f / sum, Hv = 0.f;
        #pragma unroll
        for (int i = 0; i < 8; ++i) {
            float p = e[i] * invs;
            Hv -= p * __logf(p + 1e-9f);
        }
        float H = Hv * 1.4426950408889634f;
        ushort_t hh = f2b(H);
        giH[(long)token * 576 + 512] = hh;
        giL[(long)token * 576 + 512] = f2b(H - b2f(hh));
    }
    if (lane < 63) {
        giH[(long)token * 576 + 513 + lane] = 0;
        giL[(long)token * 576 + 513 + lane] = 0;
    }
}

// ---------------------------------------------------------------------------
// LayerNorms.
// ---------------------------------------------------------------------------
__global__ __launch_bounds__(256)
void ln1_kernel(const float* __restrict__ x, const float* __restrict__ g,
                const ushort_t* __restrict__ giH, const ushort_t* __restrict__ giL,
                const float* __restrict__ gamma, const float* __restrict__ beta,
                float* __restrict__ outF, ushort_t* __restrict__ outB)
{
    __shared__ float red[8];
    long t = blockIdx.x;
    int i = threadIdx.x;
    long idx = t * 256 + i;
    float yssm  = b2f(giH[t * 576 + i])       + b2f(giL[t * 576 + i]);
    float yattn = b2f(giH[t * 576 + 256 + i]) + b2f(giL[t * 576 + 256 + i]);
    float gv = g[idx];
    float v = x[idx] + gv * yssm + (1.f - gv) * yattn;
    float s = v;
    #pragma unroll
    for (int m = 32; m; m >>= 1) s += __shfl_xor(s, m, 64);
    if ((i & 63) == 0) red[i >> 6] = s;
    __syncthreads();
    float mu = (red[0] + red[1] + red[2] + red[3]) * (1.f / 256.f);
    float dv = v - mu;
    float s2 = dv * dv;
    #pragma unroll
    for (int m = 32; m; m >>= 1) s2 += __shfl_xor(s2, m, 64);
    if ((i & 63) == 0) red[4 + (i >> 6)] = s2;
    __syncthreads();
    float var = (red[4] + red[5] + red[6] + red[7]) * (1.f / 256.f);
    float o = dv * rsqrtf(var + 1e-5f) * gamma[i] + beta[i];
    outF[idx] = o;
    outB[idx] = f2b(o);
}

__global__ __launch_bounds__(256)
void ln2_kernel(const float* __restrict__ h, const float* __restrict__ f2,
                const float* __restrict__ gamma, const float* __restrict__ beta,
                float* __restrict__ out)
{
    __shared__ float red[8];
    long t = blockIdx.x;
    int i = threadIdx.x;
    long idx = t * 256 + i;
    float v = h[idx] + f2[idx];
    float s = v;
    #pragma unroll
    for (int m = 32; m; m >>= 1) s += __shfl_xor(s, m, 64);
    if ((i & 63) == 0) red[i >> 6] = s;
    __syncthreads();
    float mu = (red[0] + red[1] + red[2] + red[3]) * (1.f / 256.f);
    float dv = v - mu;
    float s2 = dv * dv;
    #pragma unroll
    for (int m = 32; m; m >>= 1) s2 += __shfl_xor(s2, m, 64);
    if ((i & 63) == 0) red[4 + (i >> 6)] = s2;
    __syncthreads();
    float var = (red[4] + red[5] + red[6] + red[7]) * (1.f / 256.f);
    out[idx] = dv * rsqrtf(var + 1e-5f) * gamma[i] + beta[i];
}

// ---------------------------------------------------------------------------

extern "C" void kernel_launch(void* const* d_in, const int* in_sizes, int n_in,
                              void* d_out, int out_size, void* d_ws, size_t ws_size,
                              hipStream_t stream)
{
    const float* x       = (const float*)d_in[0];
    const float* A_log   = (const float*)d_in[1];
    const float* W_xproj = (const float*)d_in[2];
    const float* W_dt    = (const float*)d_in[3];
    const float* b_dt    = (const float*)d_in[4];
    const float* W_C     = (const float*)d_in[5];
    const float* Wq      = (const float*)d_in[6];
    const float* Wk      = (const float*)d_in[7];
    const float* Wv      = (const float*)d_in[8];
    const float* Wo      = (const float*)d_in[9];
    const float* omega   = (const float*)d_in[10];
    const float* Wg1     = (const float*)d_in[11];
    const float* bg1     = (const float*)d_in[12];
    const float* Wg2     = (const float*)d_in[13];
    const float* bg2     = (const float*)d_in[14];
    const float* ln1_g   = (const float*)d_in[15];
    const float* ln1_b   = (const float*)d_in[16];
    const float* ln2_g   = (const float*)d_in[17];
    const float* ln2_b   = (const float*)d_in[18];
    const float* Wf1     = (const float*)d_in[19];
    const float* bf1     = (const float*)d_in[20];
    const float* Wf2     = (const float*)d_in[21];
    const float* bf2     = (const float*)d_in[22];

    char* B = (char*)d_ws;
    float* out = (float*)d_out;
    if (ws_size < (size_t)42778624) return;

    // persistent regions
    ushort_t* x0      = (ushort_t*)(B + 0);
    ushort_t* x1      = (ushort_t*)(B + 1048576);
    ushort_t* x2      = (ushort_t*)(B + 2097152);
    ushort_t* Qp_hi   = (ushort_t*)(B + 3145728);
    ushort_t* Qp_lo   = (ushort_t*)(B + 5242880);
    ushort_t* Kp_hi   = (ushort_t*)(B + 7340032);
    ushort_t* Kp_lo   = (ushort_t*)(B + 9437184);
    ushort_t* KpT_hi  = (ushort_t*)(B + 11534336);
    ushort_t* KpT_lo  = (ushort_t*)(B + 13631488);
    ushort_t* VT_hi   = (ushort_t*)(B + 15728640);
    ushort_t* VT_lo   = (ushort_t*)(B + 16777216);
    float*    dST_f   = (float*)(B + 17825792);      // 8 MB -> 26214400
    float*    delta_f = (float*)(B + 26214400);      // 2 MB (alive until M3)
    float*    BtCt_f  = (float*)(B + 28311552);      // 256 KB (alive until M3)
    ushort_t* Wg1T0   = (ushort_t*)(B + 28573696);
    ushort_t* Wg1T1   = (ushort_t*)(B + 28868608);
    ushort_t* Wf1T    = (ushort_t*)(B + 29163520);
    ushort_t* Wf2T    = (ushort_t*)(B + 29687808);
    ushort_t* WxdT0   = (ushort_t*)(B + 30212096);
    ushort_t* WxdT1   = (ushort_t*)(B + 30343168);
    ushort_t* WvT0    = (ushort_t*)(B + 30474240);
    ushort_t* WvT1    = (ushort_t*)(B + 30605312);
    ushort_t* WoT0    = (ushort_t*)(B + 30736384);
    ushort_t* WoT1    = (ushort_t*)(B + 30867456);
    ushort_t* Wg2T0   = (ushort_t*)(B + 30998528);
    ushort_t* Wg2T1   = (ushort_t*)(B + 31129600);
    ushort_t* WdtT0   = (ushort_t*)(B + 31260672);
    ushort_t* WdtT1   = (ushort_t*)(B + 31293440);
    ushort_t* WxpP0   = (ushort_t*)(B + 31326208);
    ushort_t* WxpP1   = (ushort_t*)(B + 31358976);
    ushort_t* WbcT0   = (ushort_t*)(B + 31391744);
    ushort_t* WbcT1   = (ushort_t*)(B + 31424512);
    float*    mbuf    = (float*)(B + 31457280);
    float*    dzc     = (float*)(B + 31465472);
    ushort_t* gatein_hi = (ushort_t*)(B + 31498240); // 2048x576
    ushort_t* gatein_lo = (ushort_t*)(B + 33857536); // ends 36216832
    ushort_t* ST_lo   = (ushort_t*)(B + 36216832);   // 4 MB -> 40411136
    float*    scores_f  = (float*)(B + 40411136);    // 1 MB -> 41459712
    ushort_t* scores_hi = (ushort_t*)(B + 41459712); // 512 KB -> 41984000
    ushort_t* scores_lo = (ushort_t*)(B + 41984000); // 512 KB -> 42508288
    // aliases (lifetime-disjoint)
    ushort_t* omT0  = (ushort_t*)(B + 17825792);
    ushort_t* omT1  = (ushort_t*)(B + 17956864);
    ushort_t* omT2  = (ushort_t*)(B + 18087936);
    ushort_t* Wq0   = (ushort_t*)(B + 18219008);
    ushort_t* Wq1   = (ushort_t*)(B + 18350080);
    ushort_t* Wq2   = (ushort_t*)(B + 18481152);
    ushort_t* Wk0   = (ushort_t*)(B + 18612224);
    ushort_t* Wk1   = (ushort_t*)(B + 18743296);
    ushort_t* Wk2   = (ushort_t*)(B + 18874368);
    ushort_t* WqoT0 = (ushort_t*)(B + 19005440);
    ushort_t* WqoT1 = (ushort_t*)(B + 19136512);
    ushort_t* WqoT2 = (ushort_t*)(B + 19267584);
    ushort_t* WkoT0 = (ushort_t*)(B + 19398656);
    ushort_t* WkoT1 = (ushort_t*)(B + 19529728);
    ushort_t* WkoT2 = (ushort_t*)(B + 19660800);
    ushort_t* ST_hi = (ushort_t*)(B + 11534336);     // 4 MB over KpT (dead after M1)
    float*    hend   = (float*)(B + 0);              // over x0 (dead after K3)
    float*    Pst    = (float*)(B + 524288);
    float*    hstart = (float*)(B + 1048576);        // over x1
    float*    numA_f = (float*)(B + 17825792);       // over dST (dead after M2)
    float*    numB_f = (float*)(B + 19922944);
    ushort_t* g1_hi  = (ushort_t*)(B + 22020096);
    ushort_t* g1_lo  = (ushort_t*)(B + 23068672);
    float*    gbuf_f = (float*)(B + 24117248);
    ushort_t* ypre_hi = (ushort_t*)(B + 7340032);    // over Kp (dead after M2 dzc)
    ushort_t* ypre_lo = (ushort_t*)(B + 8388608);
    float*    hbuf_f  = (float*)(B + 11534336);      // over ST_hi (dead after M3)
    ushort_t* hbuf_b  = (ushort_t*)(B + 13631488);
    ushort_t* ffn1_b  = (ushort_t*)(B + 3145728);    // over Qp (dead after K10)
    float*    ffn2_f  = (float*)(B + 15728640);      // over VT (dead after M3)

    dim3 T256(256);
    GJob jz{};
    SJob sz{};

    // K1: convert + norms
    convert_kernel<<<dim3(CONV_BLKS + 512), T256, 0, stream>>>(x, W_xproj, W_dt, W_C,
        Wq, Wk, Wv, Wo, omega, Wg1, Wg2, Wf1, Wf2,
        x0, x1, x2, omT0, omT1, omT2, Wq0, Wq1, Wq2, Wk0, Wk1, Wk2,
        WvT0, WvT1, WoT0, WoT1, Wg1T0, Wg1T1, Wg2T0, Wg2T1, Wf1T, Wf2T,
        WdtT0, WdtT1, WxpP0, WxpP1, WbcT0, WbcT1, mbuf);

    // K2: {Wqo, Wko, Wxd}
    {
        GJob a{}; a.A0=omT0; a.A1=omT1; a.A2=omT2; a.B0=Wq0; a.B1=Wq1; a.B2=Wq2;
        a.o0=WqoT0; a.o1=WqoT1; a.o2=WqoT2; a.lda=256; a.ldb=256; a.ldob=256;
        a.act=ACT_NONE; a.ns=3; a.K=256; a.N=256; a.nx=4; a.ny=4; a.base=0; a.zmod=1;
        GJob b = a; b.B0=Wk0; b.B1=Wk1; b.B2=Wk2; b.o0=WkoT0; b.o1=WkoT1; b.o2=WkoT2; b.base=16;
        GJob c{}; c.A0=WdtT0; c.A1=WdtT1; c.B0=WxpP0; c.B1=WxpP1;
        c.o0=WxdT0; c.o1=WxdT1; c.lda=64; c.ldb=64; c.ldob=256;
        c.act=ACT_NONE; c.ns=2; c.K=64; c.N=256; c.nx=4; c.ny=4; c.base=32; c.zmod=1;
        gemm_multi<3,0><<<dim3(48), T256, 0, stream>>>(a, b, c, jz, jz, sz);
    }
    // K3: {V->VT, Qp, Kp(+KpT), BtCt, delta}
    {
        GJob v{}; v.A0=x0; v.A1=x1; v.B0=WvT0; v.B1=WvT1;
        v.t0=VT_hi; v.t1=VT_lo; v.sTb=262144;
        v.lda=256; v.ldb=256; v.act=ACT_NONE; v.ns=2; v.K=256; v.N=256;
        v.nx=4; v.ny=32; v.base=0; v.zmod=1;
        GJob q{}; q.A0=x0; q.A1=x1; q.A2=x2; q.B0=WqoT0; q.B1=WqoT1; q.B2=WqoT2;
        q.o0=Qp_hi; q.o1=Qp_lo; q.lda=256; q.ldb=256; q.ldob=512;
        q.act=ACT_RFF; q.ns=3; q.K=256; q.N=256; q.nx=4; q.ny=32; q.base=128; q.zmod=1;
        GJob k = q; k.B0=WkoT0; k.B1=WkoT1; k.B2=WkoT2; k.o0=Kp_hi; k.o1=Kp_lo;
        k.t0=KpT_hi; k.t1=KpT_lo; k.sTb=524288; k.base=256;
        GJob bc{}; bc.A0=x0; bc.A1=x1; bc.B0=WbcT0; bc.B1=WbcT1;
        bc.outF=BtCt_f; bc.lda=256; bc.ldb=256; bc.ldo=32;
        bc.act=ACT_NONE; bc.ns=2; bc.K=256; bc.N=32; bc.nx=1; bc.ny=32; bc.base=384; bc.zmod=1;
        GJob dl{}; dl.A0=x0; dl.A1=x1; dl.B0=WxdT0; dl.B1=WxdT1; dl.bias=b_dt;
        dl.outF=delta_f; dl.lda=256; dl.ldb=256; dl.ldo=256;
        dl.act=ACT_SOFTPLUS; dl.ns=2; dl.K=256; dl.N=256; dl.nx=4; dl.ny=32; dl.base=416; dl.zmod=1;
        gemm_multi<3,0><<<dim3(544), T256, 0, stream>>>(v, q, k, bc, dl, sz);
    }
    // M1: {dST, scores GEMMs} + SSM pass-1 (blocks 576..1087)
    {
        GJob d{}; d.A0=VT_hi; d.A1=VT_lo; d.B0=KpT_hi; d.B1=KpT_lo;
        d.outF=dST_f; d.lda=1024; d.ldb=1024; d.ldo=512;
        d.act=ACT_NONE; d.ns=2; d.K=128; d.N=512; d.nx=8; d.ny=4; d.base=0; d.zmod=8;
        d.sAb1=262144; d.sAb2=128; d.sBb1=524288; d.sBb2=128; d.sOb=131072;
        GJob s{}; s.A0=Qp_hi; s.A1=Qp_lo; s.B0=Kp_hi; s.B1=Kp_lo;
        s.outF=scores_f; s.o0=scores_hi; s.o1=scores_lo;
        s.lda=512; s.ldb=512; s.ldo=128; s.ldob=128;
        s.act=ACT_CAUSAL; s.ns=2; s.K=512; s.N=128; s.nx=2; s.ny=2; s.base=512; s.zmod=1;
        s.sAb1=65536; s.sBb1=65536; s.sOb=16384; s.sObB=16384;
        SJob s1{}; s1.x=x; s1.delta=delta_f; s1.BtCt=BtCt_f; s1.A_log=A_log;
        s1.hend=hend; s1.Pst=Pst; s1.base=576;
        gemm_multi<2,1><<<dim3(1088), T256, 0, stream>>>(d, s, jz, jz, jz, s1);
    }
    // M2: SSM cross-scan + K colsums + ST prefix scan
    scan_mix<<<dim3(1088), T256, 0, stream>>>(hend, Pst, hstart, Kp_hi, Kp_lo, dzc,
                                              dST_f, ST_hi, ST_lo);
    // M3: {numA, numB GEMMs} + SSM pass-3 (blocks 256..767)
    {
        GJob a{}; a.A0=scores_hi; a.A1=scores_lo; a.B0=VT_hi; a.B1=VT_lo;
        a.outF=numA_f; a.lda=128; a.ldb=1024; a.ldo=256;
        a.act=ACT_NONE; a.ns=2; a.K=128; a.N=256; a.nx=4; a.ny=2; a.base=0; a.zmod=8;
        a.sAb1=131072; a.sAb2=16384; a.sBb1=262144; a.sBb2=128; a.sOb=32768;
        GJob b{}; b.A0=Qp_hi; b.A1=Qp_lo; b.B0=ST_hi; b.B1=ST_lo;
        b.outF=numB_f; b.lda=512; b.ldb=512; b.ldo=256;
        b.act=ACT_NONE; b.ns=2; b.K=512; b.N=256; b.nx=4; b.ny=2; b.base=128; b.zmod=1;
        b.sAb1=65536; b.sBb1=131072; b.sOb=32768;
        SJob s3{}; s3.x=x; s3.delta=delta_f; s3.BtCt=BtCt_f; s3.A_log=A_log;
        s3.hstart=hstart; s3.giH=gatein_hi; s3.giL=gatein_lo; s3.base=256;
        gemm_multi<2,3><<<dim3(768), T256, 0, stream>>>(a, b, jz, jz, jz, s3);
    }
    // K10: attn_finish (+entropy, +gatein pads)
    attn_finish<<<dim3(2048), dim3(64), 0, stream>>>(scores_f, Qp_hi, Qp_lo, dzc,
        numA_f, numB_f, mbuf, ypre_hi, ypre_lo, gatein_hi, gatein_lo);
    // K11: yattn = ypre@Wo -> gatein cols 256..511
    {
        GJob w{}; w.A0=ypre_hi; w.A1=ypre_lo; w.B0=WoT0; w.B1=WoT1;
        w.o0=gatein_hi; w.o1=gatein_lo; w.colOffB=256;
        w.lda=256; w.ldb=256; w.ldob=576;
        w.act=ACT_NONE; w.ns=2; w.K=256; w.N=256; w.nx=4; w.ny=32; w.base=0; w.zmod=1;
        gemm_multi<2,0><<<dim3(128), T256, 0, stream>>>(w, jz, jz, jz, jz, sz);
    }
    // K12: g1
    {
        GJob g{}; g.A0=gatein_hi; g.A1=gatein_lo; g.B0=Wg1T0; g.B1=Wg1T1; g.bias=bg1;
        g.o0=g1_hi; g.o1=g1_lo; g.lda=576; g.ldb=576; g.ldob=256;
        g.act=ACT_SILU; g.ns=2; g.K=576; g.N=256; g.nx=4; g.ny=32; g.base=0; g.zmod=1;
        gemm_multi<2,0><<<dim3(128), T256, 0, stream>>>(g, jz, jz, jz, jz, sz);
    }
    // K13: g2
    {
        GJob g{}; g.A0=g1_hi; g.A1=g1_lo; g.B0=Wg2T0; g.B1=Wg2T1; g.bias=bg2;
        g.outF=gbuf_f; g.lda=256; g.ldb=256; g.ldo=256;
        g.act=ACT_SIGMOID; g.ns=2; g.K=256; g.N=256; g.nx=4; g.ny=32; g.base=0; g.zmod=1;
        gemm_multi<2,0><<<dim3(128), T256, 0, stream>>>(g, jz, jz, jz, jz, sz);
    }
    // K14: ln1
    ln1_kernel<<<dim3(2048), T256, 0, stream>>>(x, gbuf_f, gatein_hi, gatein_lo, ln1_g, ln1_b, hbuf_f, hbuf_b);
    // K15: FFN1
    {
        GJob f{}; f.A0=hbuf_b; f.B0=Wf1T; f.bias=bf1;
        f.o0=ffn1_b; f.lda=256; f.ldb=256; f.ldob=1024;
        f.act=ACT_GELU; f.ns=1; f.K=256; f.N=1024; f.nx=16; f.ny=32; f.base=0; f.zmod=1;
        gemm_multi<1,0><<<dim3(512), T256, 0, stream>>>(f, jz, jz, jz, jz, sz);
    }
    // K16: FFN2
    {
        GJob f{}; f.A0=ffn1_b; f.B0=Wf2T; f.bias=bf2;
        f.outF=ffn2_f; f.lda=1024; f.ldb=1024; f.ldo=256;
        f.act=ACT_NONE; f.ns=1; f.K=1024; f.N=256; f.nx=4; f.ny=32; f.base=0; f.zmod=1;
        gemm_multi<1,0><<<dim3(128), T256, 0, stream>>>(f, jz, jz, jz, jz, sz);
    }
    // K17: ln2
    ln2_kernel<<<dim3(2048), T256, 0, stream>>>(hbuf_f, ffn2_f, ln2_g, ln2_b, out);
}